// Round 12
// baseline (441.565 us; speedup 1.0000x reference)
//
#include <hip/hip_runtime.h>
#include <hip/hip_fp16.h>

#define NVN 20000
#define NCN 20000
#define NE  500000
#define HID 64
#define NLAYER 3
#define TN 40      // nodes per MLP tile (proven R2 config)
#define BSH 8      // bin shift: 256 nodes/bin
#define NB 79      // ceil(20000/256) bins
#define CAPSH 14   // bin capacity 16384 (avg fill 6329, 2.6x margin)
#define CAP (1 << CAPSH)
#define NBCAP (NB * CAP)
#define P1E 2048   // edges per scatter block -> 245 blocks
#define NTILES (NVN / TN)   // 500
#define SNAPL (NLAYER - 1)  // only layers 0..1 need snapshots; layer 2 = feat

__device__ __forceinline__ float relu_(float x) { return fmaxf(x, 0.0f); }

// ---------------- bincur init: bin b allocates from b*CAP ------------------
__global__ __launch_bounds__(256) void bininit_kernel(
    int* __restrict__ bincurA, int* __restrict__ bincurB)
{
    int t = threadIdx.x;
    if (t < NB) { bincurA[t] = t << CAPSH; bincurB[t] = t << CAPSH; }
}

// ---------------- Binned scatter pass 1: edges -> bin-staged ----------------
__global__ __launch_bounds__(256) void scatter_p1_kernel(
    const int* __restrict__ eiA, const float* __restrict__ ewA,
    int* __restrict__ bincurA, int2* __restrict__ stageA,
    const int* __restrict__ eiB, const float* __restrict__ ewB,
    int* __restrict__ bincurB, int2* __restrict__ stageB)
{
    __shared__ int rnk[P1E];            // 8 KB
    __shared__ int cnt[NB], base_[NB];
    int t = threadIdx.x;
    int e0 = blockIdx.x * P1E;

    for (int g = 0; g < 2; ++g) {
        const int* ei   = g ? eiB : eiA;
        const float* ew = g ? ewB : ewA;
        int* bincur     = g ? bincurB : bincurA;
        int2* stage     = g ? stageB : stageA;

        if (t < NB) cnt[t] = 0;
        __syncthreads();
        for (int i = t; i < P1E; i += 256) {
            int e = e0 + i;
            if (e < NE) {
                int d = ei[NE + e];
                rnk[i] = atomicAdd(&cnt[d >> BSH], 1);
            }
        }
        __syncthreads();
        if (t < NB && cnt[t] > 0) base_[t] = atomicAdd(&bincur[t], cnt[t]);
        __syncthreads();
        for (int i = t; i < P1E; i += 256) {
            int e = e0 + i;
            if (e < NE) {
                int s = ei[e], d = ei[NE + e];
                float w = ew[e];
                stage[base_[d >> BSH] + rnk[i]] =
                    make_int2((int)((unsigned)s | ((unsigned)d << 16)), __float_as_int(w));
            }
        }
        __syncthreads();
    }
}

// ---------------- Pass 2: LDS counting sort per bin ------------------------
__global__ __launch_bounds__(1024) void scatter_p2_kernel(
    const int* __restrict__ bincurA, const int2* __restrict__ stageA,
    int* __restrict__ rowptrA, int* __restrict__ rowendA, int2* __restrict__ pairA,
    const int* __restrict__ bincurB, const int2* __restrict__ stageB,
    int* __restrict__ rowptrB, int* __restrict__ rowendB, int2* __restrict__ pairB)
{
    __shared__ int deg[256], pfx[256], cur[256];
    int g = blockIdx.x / NB;
    int b = blockIdx.x % NB;
    const int* bincur  = g ? bincurB : bincurA;
    const int2* stage  = g ? stageB : stageA;
    int* rowptr        = g ? rowptrB : rowptrA;
    int* rowend        = g ? rowendB : rowendA;
    int2* pair         = g ? pairB : pairA;

    int d0 = b << BSH;
    int d1 = min(d0 + 256, NCN);   // NVN == NCN
    int nd = d1 - d0;
    int t = threadIdx.x;
    int estart = b << CAPSH;
    int eend = bincur[b];

    if (t < 256) deg[t] = 0;
    __syncthreads();
    for (int e = estart + t; e < eend; e += 1024) {
        int dst = (int)((unsigned)stage[e].x >> 16);
        atomicAdd(&deg[dst - d0], 1);
    }
    __syncthreads();
    if (t < 256) pfx[t] = deg[t];
    __syncthreads();
    for (int off = 1; off < 256; off <<= 1) {
        int v = (t >= off && t < 256) ? pfx[t - off] : 0;
        __syncthreads();
        if (t < 256) pfx[t] += v;
        __syncthreads();
    }
    if (t < nd) {
        int ex = estart + pfx[t] - deg[t];   // exclusive
        rowptr[d0 + t] = ex;
        rowend[d0 + t] = estart + pfx[t];
        cur[t] = ex;
    }
    __syncthreads();
    for (int e = estart + t; e < eend; e += 1024) {
        int2 s = stage[e];
        unsigned u = (unsigned)s.x;
        int src = (int)(u & 0xFFFFu);
        int dst = (int)(u >> 16);
        int p = atomicAdd(&cur[dst - d0], 1);
        pair[p] = make_int2(src, s.y);
    }
}

// ---------------- Encoders (both node sets; fp32 + fp16 mirror out) --------
__global__ __launch_bounds__(256) void encode2_kernel(
    const float* __restrict__ xv, const float* __restrict__ pev,
    const float* __restrict__ ewv, const float* __restrict__ ebv,
    const float* __restrict__ pw1v, const float* __restrict__ pb1v,
    const float* __restrict__ pw2v, const float* __restrict__ pb2v,
    const float* __restrict__ xc, const float* __restrict__ pec,
    const float* __restrict__ ewc, const float* __restrict__ ebc,
    const float* __restrict__ pw1c, const float* __restrict__ pb1c,
    const float* __restrict__ pw2c, const float* __restrict__ pb2c,
    float* __restrict__ outv, float* __restrict__ outc,
    __half* __restrict__ outv16, __half* __restrict__ outc16)
{
    __shared__ float sh[4][64];
    const int VB = (NVN + 3) / 4;
    int wave = threadIdx.x >> 6, lane = threadIdx.x & 63;
    int b = blockIdx.x;
    bool isC = (b >= VB);
    const float* x   = isC ? xc : xv;
    const float* pe  = isC ? pec : pev;
    const float* ew  = isC ? ewc : ewv;
    const float* eb  = isC ? ebc : ebv;
    const float* pw1 = isC ? pw1c : pw1v;
    const float* pb1 = isC ? pb1c : pb1v;
    const float* pw2 = isC ? pw2c : pw2v;
    const float* pb2 = isC ? pb2c : pb2v;
    float* out = isC ? outc : outv;
    __half* out16 = isC ? outc16 : outv16;
    int N = isC ? NCN : NVN;
    int n = (isC ? b - VB : b) * 4 + wave;
    if (n >= N) return;

    float accp = pb1[lane], accm = accp;
#pragma unroll
    for (int k = 0; k < 8; ++k) {
        float p = pe[n * 8 + k];
        float w = pw1[k * 64 + lane];
        accp += p * w;
        accm -= p * w;
    }
    float hs = 0.5f * (relu_(accp) + relu_(accm));
    float* my = sh[wave];
    my[lane] = hs;
    __builtin_amdgcn_wave_barrier();

    int col = lane & 31;
    float peo = pb2[col];
#pragma unroll
    for (int k = 0; k < 64; k += 4) {
        float4 hv = *(const float4*)(my + k);
        peo = fmaf(hv.x, pw2[(k + 0) * 32 + col], peo);
        peo = fmaf(hv.y, pw2[(k + 1) * 32 + col], peo);
        peo = fmaf(hv.z, pw2[(k + 2) * 32 + col], peo);
        peo = fmaf(hv.w, pw2[(k + 3) * 32 + col], peo);
    }
    float lino = x[n * 2 + 0] * ew[col] + x[n * 2 + 1] * ew[32 + col] + eb[col];
    float h = (lane < 32) ? lino : peo;
    float r = relu_(h);
    out[n * 64 + lane] = r;
    out16[n * 64 + lane] = __float2half(r);
}

// ---------------- Edge aggregation: half2 DUAL-EDGE gathers ----------------
// Lane-group g = lane>>5 owns edge j+2c+g; each lane loads half2 (2 dims).
// One gather instruction covers 2 edges (256 B) -> gather instrs halved vs
// R8 while PIPELINE DEPTH in edges doubles (16 in flight per 8 loads).
// Same VALU (16 exp/lane per 16 edges). den/num are per-dim; the two edge
// groups merge with shfl_xor(32) at the end; lanes 0-31 store float2.
__global__ __launch_bounds__(256, 8) void edge_agg_kernel(
    const __half* __restrict__ xsrc,  // [Nsrc,64] fp16 mirror
    const float* __restrict__ xdst,   // [Ndst,64] fp32
    const int* __restrict__ rowptr,   // [Ndst]
    const int* __restrict__ rowend,   // [Ndst]
    const int2* __restrict__ pair,    // gapped, dst-sorted
    const float* __restrict__ lew,    // [64]
    const float* __restrict__ leb,    // [64]
    float* __restrict__ oa,           // [Ndst,64]  agg + xdst
    int N)
{
    int wave = threadIdx.x >> 6, lane = threadIdx.x & 63;
    int n = blockIdx.x * 4 + wave;
    if (n >= N) return;

    int start = __builtin_amdgcn_readfirstlane(rowptr[n]);
    int end   = __builtin_amdgcn_readfirstlane(rowend[n]);
    int g  = lane >> 5;        // edge slot within a dual-gather
    int d  = lane & 31;        // dim-pair index (dims 2d, 2d+1)
    const unsigned* xs2 = (const unsigned*)xsrc;   // half2 as u32
    float lw0 = lew[d * 2], lw1 = lew[d * 2 + 1];
    float lb0 = leb[d * 2], lb1 = leb[d * 2 + 1];
    float2 xd2 = ((const float2*)xdst)[(size_t)n * 32 + d];

    float den0 = 0.0f, den1 = 0.0f, num0 = 0.0f, num1 = 0.0f;
    int j = start;

#define EDGE2(P, U) { \
        __half2 h2 = *(const __half2*)&(U); \
        float2 xf = __half22float2(h2); \
        float w_ = __int_as_float((P).y); \
        float m0 = relu_(fmaf(w_, lw0, xf.x + lb0)) + 1e-7f; \
        float m1 = relu_(fmaf(w_, lw1, xf.y + lb1)) + 1e-7f; \
        float e0 = __expf(m0), e1 = __expf(m1); \
        den0 += e0; num0 = fmaf(e0, m0, num0); \
        den1 += e1; num1 = fmaf(e1, m1, num1); }

    if (j + 16 <= end) {
        int2 pb[8];
#pragma unroll
        for (int c = 0; c < 8; ++c) pb[c] = pair[j + 2 * c + g];

        for (; j + 32 <= end; j += 16) {
            unsigned xv[8];
#pragma unroll
            for (int c = 0; c < 8; ++c)
                xv[c] = xs2[(size_t)pb[c].x * 32 + d];
            int2 pn[8];
#pragma unroll
            for (int c = 0; c < 8; ++c) pn[c] = pair[j + 16 + 2 * c + g];
#pragma unroll
            for (int c = 0; c < 8; ++c) EDGE2(pb[c], xv[c]);
#pragma unroll
            for (int c = 0; c < 8; ++c) pb[c] = pn[c];
        }
        {   // last full 16 (pairs already in registers)
            unsigned xv[8];
#pragma unroll
            for (int c = 0; c < 8; ++c)
                xv[c] = xs2[(size_t)pb[c].x * 32 + d];
#pragma unroll
            for (int c = 0; c < 8; ++c) EDGE2(pb[c], xv[c]);
            j += 16;
        }
    }
    for (; j + 2 <= end; j += 2) {
        int2 p = pair[j + g];
        unsigned u = xs2[(size_t)p.x * 32 + d];
        EDGE2(p, u);
    }
    if (j < end) {   // one leftover edge: group 1 contributes zero
        int2 p = pair[j];
        unsigned u = xs2[(size_t)p.x * 32 + d];
        __half2 h2 = *(const __half2*)&u;
        float2 xf = __half22float2(h2);
        float w_ = __int_as_float(p.y);
        float m0 = relu_(fmaf(w_, lw0, xf.x + lb0)) + 1e-7f;
        float m1 = relu_(fmaf(w_, lw1, xf.y + lb1)) + 1e-7f;
        float e0 = (g == 0) ? __expf(m0) : 0.0f;
        float e1 = (g == 0) ? __expf(m1) : 0.0f;
        den0 += e0; num0 = fmaf(e0, m0, num0);
        den1 += e1; num1 = fmaf(e1, m1, num1);
    }
#undef EDGE2

    // merge the two edge groups (lanes m and m+32 hold the same dims)
    den0 += __shfl_xor(den0, 32, 64);
    den1 += __shfl_xor(den1, 32, 64);
    num0 += __shfl_xor(num0, 32, 64);
    num1 += __shfl_xor(num1, 32, 64);

    if (lane < 32) {
        float2 r;
        r.x = num0 / (den0 + 1e-16f) + xd2.x;
        r.y = num1 / (den1 + 1e-16f) + xd2.y;
        ((float2*)oa)[(size_t)n * 32 + d] = r;
    }
}

// ---------------- MLP (pred head extracted): 64->128->64 -------------------
__global__ __launch_bounds__(256, 4) void mlp_kernel(
    const float* __restrict__ oa,    // [N,64]
    float* __restrict__ feat,        // [N,64]
    __half* __restrict__ feat16,     // [N,64] fp16 mirror
    float* __restrict__ snap,        // [N,64] snapshot or nullptr
    const float* __restrict__ w1,    // [64,128]
    const float* __restrict__ b1,    // [128]
    const float* __restrict__ w2,    // [128,64]
    const float* __restrict__ b2,    // [64]
    int N)
{
    __shared__ float act[TN][68];
    __shared__ float hid[TN][132];
    __shared__ float b1s[128];
    __shared__ float b2s[64];

    int tid = threadIdx.x;
    if (tid < 128) b1s[tid] = b1[tid];
    if (tid < 64) b2s[tid] = b2[tid];

    int o4 = (tid & 31) * 4;
    int o2 = (tid & 31) * 2;
    int n5 = (tid >> 5) * 5;
    __syncthreads();

    int ntiles = N / TN;
    for (int tile = blockIdx.x; tile < ntiles; tile += gridDim.x) {
        int base = tile * TN;
        {
            const float4* g4 = (const float4*)(oa + (size_t)base * 64);
            for (int i = tid; i < TN * 16; i += 256)
                *(float4*)&act[i >> 4][(i & 15) * 4] = g4[i];
        }
        __syncthreads();

        {
            float acc[5][4];
#pragma unroll
            for (int i = 0; i < 5; ++i)
#pragma unroll
                for (int q = 0; q < 4; ++q) acc[i][q] = b1s[o4 + q];
#pragma unroll 2
            for (int k = 0; k < 64; k += 4) {
                float4 a[5];
#pragma unroll
                for (int i = 0; i < 5; ++i) a[i] = *(const float4*)&act[n5 + i][k];
                float4 w0 = *(const float4*)&w1[(k + 0) * 128 + o4];
                float4 wq1 = *(const float4*)&w1[(k + 1) * 128 + o4];
                float4 wq2 = *(const float4*)&w1[(k + 2) * 128 + o4];
                float4 wq3 = *(const float4*)&w1[(k + 3) * 128 + o4];
#pragma unroll
                for (int i = 0; i < 5; ++i) {
                    acc[i][0] = fmaf(a[i].x, w0.x, acc[i][0]);
                    acc[i][1] = fmaf(a[i].x, w0.y, acc[i][1]);
                    acc[i][2] = fmaf(a[i].x, w0.z, acc[i][2]);
                    acc[i][3] = fmaf(a[i].x, w0.w, acc[i][3]);
                    acc[i][0] = fmaf(a[i].y, wq1.x, acc[i][0]);
                    acc[i][1] = fmaf(a[i].y, wq1.y, acc[i][1]);
                    acc[i][2] = fmaf(a[i].y, wq1.z, acc[i][2]);
                    acc[i][3] = fmaf(a[i].y, wq1.w, acc[i][3]);
                    acc[i][0] = fmaf(a[i].z, wq2.x, acc[i][0]);
                    acc[i][1] = fmaf(a[i].z, wq2.y, acc[i][1]);
                    acc[i][2] = fmaf(a[i].z, wq2.z, acc[i][2]);
                    acc[i][3] = fmaf(a[i].z, wq2.w, acc[i][3]);
                    acc[i][0] = fmaf(a[i].w, wq3.x, acc[i][0]);
                    acc[i][1] = fmaf(a[i].w, wq3.y, acc[i][1]);
                    acc[i][2] = fmaf(a[i].w, wq3.z, acc[i][2]);
                    acc[i][3] = fmaf(a[i].w, wq3.w, acc[i][3]);
                }
            }
#pragma unroll
            for (int i = 0; i < 5; ++i) {
                float4 h4 = make_float4(relu_(acc[i][0]), relu_(acc[i][1]),
                                        relu_(acc[i][2]), relu_(acc[i][3]));
                *(float4*)&hid[n5 + i][o4] = h4;
            }
        }
        __syncthreads();

        {
            float acc[5][2];
#pragma unroll
            for (int i = 0; i < 5; ++i) { acc[i][0] = b2s[o2]; acc[i][1] = b2s[o2 + 1]; }
#pragma unroll 2
            for (int k = 0; k < 128; k += 4) {
                float4 a[5];
#pragma unroll
                for (int i = 0; i < 5; ++i) a[i] = *(const float4*)&hid[n5 + i][k];
                float2 w0 = *(const float2*)&w2[(k + 0) * 64 + o2];
                float2 wq1 = *(const float2*)&w2[(k + 1) * 64 + o2];
                float2 wq2 = *(const float2*)&w2[(k + 2) * 64 + o2];
                float2 wq3 = *(const float2*)&w2[(k + 3) * 64 + o2];
#pragma unroll
                for (int i = 0; i < 5; ++i) {
                    acc[i][0] = fmaf(a[i].x, w0.x, acc[i][0]);
                    acc[i][1] = fmaf(a[i].x, w0.y, acc[i][1]);
                    acc[i][0] = fmaf(a[i].y, wq1.x, acc[i][0]);
                    acc[i][1] = fmaf(a[i].y, wq1.y, acc[i][1]);
                    acc[i][0] = fmaf(a[i].z, wq2.x, acc[i][0]);
                    acc[i][1] = fmaf(a[i].z, wq2.y, acc[i][1]);
                    acc[i][0] = fmaf(a[i].w, wq3.x, acc[i][0]);
                    acc[i][1] = fmaf(a[i].w, wq3.y, acc[i][1]);
                }
            }
#pragma unroll
            for (int i = 0; i < 5; ++i) {
                float2 r2 = make_float2(acc[i][0], acc[i][1]);
                size_t off = (size_t)(base + n5 + i) * 64 + o2;
                *(float2*)&feat[off] = r2;
                if (snap) *(float2*)&snap[off] = r2;
                *(__half2*)&feat16[off] = __floats2half2_rn(r2.x, r2.y);
            }
        }
        __syncthreads();
    }
}

// ---------------- Batched pred head: all 6 (side,layer) sources ------------
__global__ __launch_bounds__(256, 4) void pred_kernel(
    const float* __restrict__ snap,   // [2][SNAPL][N*64]
    const float* __restrict__ featv,  // [N*64] layer-2 vals
    const float* __restrict__ featc,  // [N*64] layer-2 cons
    const float* __restrict__ pv_w1, const float* __restrict__ pv_b1,
    const float* __restrict__ pv_w2, const float* __restrict__ pv_b2,
    const float* __restrict__ pc_w1, const float* __restrict__ pc_b1,
    const float* __restrict__ pc_w2, const float* __restrict__ pc_b2,
    float* __restrict__ out)          // [2][N*NLAYER]
{
    __shared__ float act[TN][68];
    __shared__ float pb1s[64];
    __shared__ float pw2s[64];

    int bid = blockIdx.x;
    int side  = bid / (NLAYER * NTILES);          // 0 = vals, 1 = cons
    int rem   = bid % (NLAYER * NTILES);
    int layer = rem / NTILES;
    int tile  = rem % NTILES;

    const float* pw1 = side ? pc_w1 : pv_w1;
    const float* pb1 = side ? pc_b1 : pv_b1;
    const float* pw2 = side ? pc_w2 : pv_w2;
    const float* pb2 = side ? pc_b2 : pv_b2;
    const float* src;
    if (layer == NLAYER - 1)
        src = side ? featc : featv;
    else
        src = snap + ((size_t)side * SNAPL + layer) * ((size_t)NVN * 64);
    float* outp = out + (size_t)side * NVN * NLAYER;

    int tid = threadIdx.x;
    if (tid < 64) { pb1s[tid] = pb1[tid]; pw2s[tid] = pw2[tid]; }
    float pb2v = pb2[0];

    int o2 = (tid & 31) * 2;
    int n5 = (tid >> 5) * 5;
    int base = tile * TN;

    {
        const float4* g4 = (const float4*)(src + (size_t)base * 64);
        for (int i = tid; i < TN * 16; i += 256)
            *(float4*)&act[i >> 4][(i & 15) * 4] = g4[i];
    }
    __syncthreads();

    float acc[5][2];
#pragma unroll
    for (int i = 0; i < 5; ++i) { acc[i][0] = pb1s[o2]; acc[i][1] = pb1s[o2 + 1]; }
#pragma unroll 2
    for (int k = 0; k < 64; k += 4) {
        float4 a[5];
#pragma unroll
        for (int i = 0; i < 5; ++i) a[i] = *(const float4*)&act[n5 + i][k];
        float2 w0 = *(const float2*)&pw1[(k + 0) * 64 + o2];
        float2 wq1 = *(const float2*)&pw1[(k + 1) * 64 + o2];
        float2 wq2 = *(const float2*)&pw1[(k + 2) * 64 + o2];
        float2 wq3 = *(const float2*)&pw1[(k + 3) * 64 + o2];
#pragma unroll
        for (int i = 0; i < 5; ++i) {
            acc[i][0] = fmaf(a[i].x, w0.x, acc[i][0]);
            acc[i][1] = fmaf(a[i].x, w0.y, acc[i][1]);
            acc[i][0] = fmaf(a[i].y, wq1.x, acc[i][0]);
            acc[i][1] = fmaf(a[i].y, wq1.y, acc[i][1]);
            acc[i][0] = fmaf(a[i].z, wq2.x, acc[i][0]);
            acc[i][1] = fmaf(a[i].z, wq2.y, acc[i][1]);
            acc[i][0] = fmaf(a[i].w, wq3.x, acc[i][0]);
            acc[i][1] = fmaf(a[i].w, wq3.y, acc[i][1]);
        }
    }
    float pw2a = pw2s[o2], pw2b = pw2s[o2 + 1];
    float ps[5];
#pragma unroll
    for (int i = 0; i < 5; ++i)
        ps[i] = relu_(acc[i][0]) * pw2a + relu_(acc[i][1]) * pw2b;
#pragma unroll
    for (int msk = 16; msk >= 1; msk >>= 1) {
#pragma unroll
        for (int i = 0; i < 5; ++i)
            ps[i] += __shfl_xor(ps[i], msk, 64);
    }
    if ((tid & 31) == 0) {
#pragma unroll
        for (int i = 0; i < 5; ++i)
            outp[(size_t)(base + n5 + i) * NLAYER + layer] = ps[i] + pb2v;
    }
}

extern "C" void kernel_launch(void* const* d_in, const int* in_sizes, int n_in,
                              void* d_out, int out_size, void* d_ws, size_t ws_size,
                              hipStream_t stream)
{
    const float* x_vals   = (const float*)d_in[0];
    const float* x_cons   = (const float*)d_in[1];
    const float* pe_vals  = (const float*)d_in[2];
    const float* pe_cons  = (const float*)d_in[3];
    const int*   ei_v2c   = (const int*)d_in[4];   // [2,E]
    const int*   ei_c2v   = (const int*)d_in[5];   // [2,E]
    const float* ew_v2c   = (const float*)d_in[6]; // [E,1]
    const float* ew_c2v   = (const float*)d_in[7];
    const float* enc_vals_w = (const float*)d_in[8];
    const float* enc_vals_b = (const float*)d_in[9];
    const float* pe_vals_w1 = (const float*)d_in[10];
    const float* pe_vals_b1 = (const float*)d_in[11];
    const float* pe_vals_w2 = (const float*)d_in[12];
    const float* pe_vals_b2 = (const float*)d_in[13];
    const float* enc_cons_w = (const float*)d_in[14];
    const float* enc_cons_b = (const float*)d_in[15];
    const float* pe_cons_w1 = (const float*)d_in[16];
    const float* pe_cons_b1 = (const float*)d_in[17];
    const float* pe_cons_w2 = (const float*)d_in[18];
    const float* pe_cons_b2 = (const float*)d_in[19];
    const float* v2c_edge_w = (const float*)d_in[20]; // [NL,1,64]
    const float* v2c_edge_b = (const float*)d_in[21]; // [NL,64]
    const float* v2c_w1     = (const float*)d_in[22]; // [NL,64,128]
    const float* v2c_b1     = (const float*)d_in[23]; // [NL,128]
    const float* v2c_w2     = (const float*)d_in[24]; // [NL,128,64]
    const float* v2c_b2     = (const float*)d_in[25]; // [NL,64]
    const float* c2v_edge_w = (const float*)d_in[26];
    const float* c2v_edge_b = (const float*)d_in[27];
    const float* c2v_w1     = (const float*)d_in[28];
    const float* c2v_b1     = (const float*)d_in[29];
    const float* c2v_w2     = (const float*)d_in[30];
    const float* c2v_b2     = (const float*)d_in[31];
    const float* pred_vals_w1 = (const float*)d_in[32];
    const float* pred_vals_b1 = (const float*)d_in[33];
    const float* pred_vals_w2 = (const float*)d_in[34];
    const float* pred_vals_b2 = (const float*)d_in[35];
    const float* pred_cons_w1 = (const float*)d_in[36];
    const float* pred_cons_b1 = (const float*)d_in[37];
    const float* pred_cons_w2 = (const float*)d_in[38];
    const float* pred_cons_b2 = (const float*)d_in[39];

    float* out = (float*)d_out;

    const size_t NF = (size_t)NVN * 64;

    // Workspace layout == R8's proven footprint (no growth).
    // snap (2 x SNAPL x NF = 20.48 MB) aliases the stage buffers (20.71 MB):
    // stage is dead after scatter_p2, before any mlp.
    float* ws     = (float*)d_ws;
    float* feat_v = ws;                 // NF
    float* feat_c = feat_v + NF;        // NF
    float* oa     = feat_c + NF;        // NF
    int2* v2c_pair  = (int2*)(oa + NF);        // NBCAP
    int2* c2v_pair  = v2c_pair + NBCAP;        // NBCAP
    int2* v2c_stage = c2v_pair + NBCAP;        // NBCAP
    int2* c2v_stage = v2c_stage + NBCAP;       // NBCAP (contiguous w/ v2c_stage)
    float* snap = (float*)v2c_stage;           // alias: [2][SNAPL][NF]
    __half* feat16_v = (__half*)(c2v_stage + NBCAP);   // NF halfs
    __half* feat16_c = feat16_v + NF;                  // NF halfs
    int* ip = (int*)(feat16_c + NF);
    int* v2c_bincur  = ip; ip += NB;
    int* c2v_bincur  = ip; ip += NB;
    int* v2c_rowptr  = ip; ip += NCN;
    int* v2c_rowend  = ip; ip += NCN;
    int* c2v_rowptr  = ip; ip += NVN;
    int* c2v_rowend  = ip; ip += NVN;

    const int p1b = (NE + P1E - 1) / P1E;   // 245

    // CSR build (single-pass binning: no histogram/scan passes)
    bininit_kernel<<<1, 256, 0, stream>>>(v2c_bincur, c2v_bincur);
    scatter_p1_kernel<<<p1b, 256, 0, stream>>>(
        ei_v2c, ew_v2c, v2c_bincur, v2c_stage,
        ei_c2v, ew_c2v, c2v_bincur, c2v_stage);
    scatter_p2_kernel<<<2 * NB, 1024, 0, stream>>>(
        v2c_bincur, v2c_stage, v2c_rowptr, v2c_rowend, v2c_pair,
        c2v_bincur, c2v_stage, c2v_rowptr, c2v_rowend, c2v_pair);

    // Encoders
    encode2_kernel<<<(NVN + 3) / 4 + (NCN + 3) / 4, 256, 0, stream>>>(
        x_vals, pe_vals, enc_vals_w, enc_vals_b,
        pe_vals_w1, pe_vals_b1, pe_vals_w2, pe_vals_b2,
        x_cons, pe_cons, enc_cons_w, enc_cons_b,
        pe_cons_w1, pe_cons_b1, pe_cons_w2, pe_cons_b2,
        feat_v, feat_c, feat16_v, feat16_c);

    for (int i = 0; i < NLAYER; ++i) {
        float* snap_c = (i < SNAPL) ? snap + ((size_t)SNAPL + i) * NF : nullptr;
        float* snap_v = (i < SNAPL) ? snap + (size_t)i * NF : nullptr;
        // v2c: src = vals (fp16 mirror), dst = cons
        edge_agg_kernel<<<(NCN + 3) / 4, 256, 0, stream>>>(
            feat16_v, feat_c, v2c_rowptr, v2c_rowend, v2c_pair,
            v2c_edge_w + (size_t)i * HID, v2c_edge_b + (size_t)i * HID,
            oa, NCN);
        mlp_kernel<<<NCN / TN, 256, 0, stream>>>(
            oa, feat_c, feat16_c, snap_c,
            v2c_w1 + (size_t)i * 8192, v2c_b1 + (size_t)i * 128,
            v2c_w2 + (size_t)i * 8192, v2c_b2 + (size_t)i * 64,
            NCN);
        // c2v: src = cons (updated fp16 mirror), dst = vals
        edge_agg_kernel<<<(NVN + 3) / 4, 256, 0, stream>>>(
            feat16_c, feat_v, c2v_rowptr, c2v_rowend, c2v_pair,
            c2v_edge_w + (size_t)i * HID, c2v_edge_b + (size_t)i * HID,
            oa, NVN);
        mlp_kernel<<<NVN / TN, 256, 0, stream>>>(
            oa, feat_v, feat16_v, snap_v,
            c2v_w1 + (size_t)i * 8192, c2v_b1 + (size_t)i * 128,
            c2v_w2 + (size_t)i * 8192, c2v_b2 + (size_t)i * 64,
            NVN);
    }

    // Batched pred head over all 6 (side,layer) sources
    pred_kernel<<<2 * NLAYER * NTILES, 256, 0, stream>>>(
        snap, feat_v, feat_c,
        pred_vals_w1, pred_vals_b1, pred_vals_w2, pred_vals_b2,
        pred_cons_w1, pred_cons_b1, pred_cons_w2, pred_cons_b2,
        out);
}

// Round 13
// 422.118 us; speedup vs baseline: 1.0461x; 1.0461x over previous
//
#include <hip/hip_runtime.h>
#include <hip/hip_fp16.h>

#define NVN 20000
#define NCN 20000
#define NE  500000
#define HID 64
#define NLAYER 3
#define TN 40      // nodes per MLP tile (proven R2 config)
#define BSH 8      // bin shift: 256 nodes/bin
#define NB 79      // ceil(20000/256) bins
#define CAPSH 14   // bin capacity 16384 (avg fill 6329, 2.6x margin)
#define CAP (1 << CAPSH)
#define NBCAP (NB * CAP)
#define P1E 2048   // edges per scatter block -> 245 blocks
#define NTILES (NVN / TN)   // 500
#define SNAPL (NLAYER - 1)  // only layers 0..1 need snapshots; layer 2 = feat

__device__ __forceinline__ float relu_(float x) { return fmaxf(x, 0.0f); }

// ---------------- bincur init: bin b allocates from b*CAP ------------------
__global__ __launch_bounds__(256) void bininit_kernel(
    int* __restrict__ bincurA, int* __restrict__ bincurB)
{
    int t = threadIdx.x;
    if (t < NB) { bincurA[t] = t << CAPSH; bincurB[t] = t << CAPSH; }
}

// ---------------- Binned scatter pass 1: edges -> bin-staged ----------------
__global__ __launch_bounds__(256) void scatter_p1_kernel(
    const int* __restrict__ eiA, const float* __restrict__ ewA,
    int* __restrict__ bincurA, int2* __restrict__ stageA,
    const int* __restrict__ eiB, const float* __restrict__ ewB,
    int* __restrict__ bincurB, int2* __restrict__ stageB)
{
    __shared__ int rnk[P1E];            // 8 KB
    __shared__ int cnt[NB], base_[NB];
    int t = threadIdx.x;
    int e0 = blockIdx.x * P1E;

    for (int g = 0; g < 2; ++g) {
        const int* ei   = g ? eiB : eiA;
        const float* ew = g ? ewB : ewA;
        int* bincur     = g ? bincurB : bincurA;
        int2* stage     = g ? stageB : stageA;

        if (t < NB) cnt[t] = 0;
        __syncthreads();
        for (int i = t; i < P1E; i += 256) {
            int e = e0 + i;
            if (e < NE) {
                int d = ei[NE + e];
                rnk[i] = atomicAdd(&cnt[d >> BSH], 1);
            }
        }
        __syncthreads();
        if (t < NB && cnt[t] > 0) base_[t] = atomicAdd(&bincur[t], cnt[t]);
        __syncthreads();
        for (int i = t; i < P1E; i += 256) {
            int e = e0 + i;
            if (e < NE) {
                int s = ei[e], d = ei[NE + e];
                float w = ew[e];
                stage[base_[d >> BSH] + rnk[i]] =
                    make_int2((int)((unsigned)s | ((unsigned)d << 16)), __float_as_int(w));
            }
        }
        __syncthreads();
    }
}

// ---------------- Pass 2: LDS counting sort per bin ------------------------
__global__ __launch_bounds__(1024) void scatter_p2_kernel(
    const int* __restrict__ bincurA, const int2* __restrict__ stageA,
    int* __restrict__ rowptrA, int* __restrict__ rowendA, int2* __restrict__ pairA,
    const int* __restrict__ bincurB, const int2* __restrict__ stageB,
    int* __restrict__ rowptrB, int* __restrict__ rowendB, int2* __restrict__ pairB)
{
    __shared__ int deg[256], pfx[256], cur[256];
    int g = blockIdx.x / NB;
    int b = blockIdx.x % NB;
    const int* bincur  = g ? bincurB : bincurA;
    const int2* stage  = g ? stageB : stageA;
    int* rowptr        = g ? rowptrB : rowptrA;
    int* rowend        = g ? rowendB : rowendA;
    int2* pair         = g ? pairB : pairA;

    int d0 = b << BSH;
    int d1 = min(d0 + 256, NCN);   // NVN == NCN
    int nd = d1 - d0;
    int t = threadIdx.x;
    int estart = b << CAPSH;
    int eend = bincur[b];

    if (t < 256) deg[t] = 0;
    __syncthreads();
    for (int e = estart + t; e < eend; e += 1024) {
        int dst = (int)((unsigned)stage[e].x >> 16);
        atomicAdd(&deg[dst - d0], 1);
    }
    __syncthreads();
    if (t < 256) pfx[t] = deg[t];
    __syncthreads();
    for (int off = 1; off < 256; off <<= 1) {
        int v = (t >= off && t < 256) ? pfx[t - off] : 0;
        __syncthreads();
        if (t < 256) pfx[t] += v;
        __syncthreads();
    }
    if (t < nd) {
        int ex = estart + pfx[t] - deg[t];   // exclusive
        rowptr[d0 + t] = ex;
        rowend[d0 + t] = estart + pfx[t];
        cur[t] = ex;
    }
    __syncthreads();
    for (int e = estart + t; e < eend; e += 1024) {
        int2 s = stage[e];
        unsigned u = (unsigned)s.x;
        int src = (int)(u & 0xFFFFu);
        int dst = (int)(u >> 16);
        int p = atomicAdd(&cur[dst - d0], 1);
        pair[p] = make_int2(src, s.y);
    }
}

// ---------------- Encoders (both node sets; fp32 + fp16 mirror out) --------
__global__ __launch_bounds__(256) void encode2_kernel(
    const float* __restrict__ xv, const float* __restrict__ pev,
    const float* __restrict__ ewv, const float* __restrict__ ebv,
    const float* __restrict__ pw1v, const float* __restrict__ pb1v,
    const float* __restrict__ pw2v, const float* __restrict__ pb2v,
    const float* __restrict__ xc, const float* __restrict__ pec,
    const float* __restrict__ ewc, const float* __restrict__ ebc,
    const float* __restrict__ pw1c, const float* __restrict__ pb1c,
    const float* __restrict__ pw2c, const float* __restrict__ pb2c,
    float* __restrict__ outv, float* __restrict__ outc,
    __half* __restrict__ outv16, __half* __restrict__ outc16)
{
    __shared__ float sh[4][64];
    const int VB = (NVN + 3) / 4;
    int wave = threadIdx.x >> 6, lane = threadIdx.x & 63;
    int b = blockIdx.x;
    bool isC = (b >= VB);
    const float* x   = isC ? xc : xv;
    const float* pe  = isC ? pec : pev;
    const float* ew  = isC ? ewc : ewv;
    const float* eb  = isC ? ebc : ebv;
    const float* pw1 = isC ? pw1c : pw1v;
    const float* pb1 = isC ? pb1c : pb1v;
    const float* pw2 = isC ? pw2c : pw2v;
    const float* pb2 = isC ? pb2c : pb2v;
    float* out = isC ? outc : outv;
    __half* out16 = isC ? outc16 : outv16;
    int N = isC ? NCN : NVN;
    int n = (isC ? b - VB : b) * 4 + wave;
    if (n >= N) return;

    float accp = pb1[lane], accm = accp;
#pragma unroll
    for (int k = 0; k < 8; ++k) {
        float p = pe[n * 8 + k];
        float w = pw1[k * 64 + lane];
        accp += p * w;
        accm -= p * w;
    }
    float hs = 0.5f * (relu_(accp) + relu_(accm));
    float* my = sh[wave];
    my[lane] = hs;
    __builtin_amdgcn_wave_barrier();

    int col = lane & 31;
    float peo = pb2[col];
#pragma unroll
    for (int k = 0; k < 64; k += 4) {
        float4 hv = *(const float4*)(my + k);
        peo = fmaf(hv.x, pw2[(k + 0) * 32 + col], peo);
        peo = fmaf(hv.y, pw2[(k + 1) * 32 + col], peo);
        peo = fmaf(hv.z, pw2[(k + 2) * 32 + col], peo);
        peo = fmaf(hv.w, pw2[(k + 3) * 32 + col], peo);
    }
    float lino = x[n * 2 + 0] * ew[col] + x[n * 2 + 1] * ew[32 + col] + eb[col];
    float h = (lane < 32) ? lino : peo;
    float r = relu_(h);
    out[n * 64 + lane] = r;
    out16[n * 64 + lane] = __float2half(r);
}

// ---------------- Edge aggregation: 8-deep pipeline, fp16 gathers ----------
// Final form: every software knob (TLP x2, bytes /2, VMEM instrs /2 and /4,
// dual-edge packing) has been probed; this structure is the measured optimum.
__global__ __launch_bounds__(256, 8) void edge_agg_kernel(
    const __half* __restrict__ xsrc,  // [Nsrc,64] fp16 mirror
    const float* __restrict__ xdst,   // [Ndst,64] fp32
    const int* __restrict__ rowptr,   // [Ndst]
    const int* __restrict__ rowend,   // [Ndst]
    const int2* __restrict__ pair,    // gapped, dst-sorted
    const float* __restrict__ lew,    // [64]
    const float* __restrict__ leb,    // [64]
    float* __restrict__ oa,           // [Ndst,64]  agg + xdst
    int N)
{
    int wave = threadIdx.x >> 6, lane = threadIdx.x & 63;
    int n = blockIdx.x * 4 + wave;
    if (n >= N) return;

    int start = __builtin_amdgcn_readfirstlane(rowptr[n]);
    int end   = __builtin_amdgcn_readfirstlane(rowend[n]);
    float lw = lew[lane], lb = leb[lane];
    float xd = xdst[(size_t)n * 64 + lane];   // independent: issue early

    float den = 0.0f, num = 0.0f;
    int j = start;

    if (j + 8 <= end) {
        int2 pb[8];
#pragma unroll
        for (int c = 0; c < 8; ++c) pb[c] = pair[j + c];

        for (; j + 16 <= end; j += 8) {
            float xv[8];
#pragma unroll
            for (int c = 0; c < 8; ++c)
                xv[c] = __half2float(xsrc[(size_t)pb[c].x * 64 + lane]);
            int2 pn[8];
#pragma unroll
            for (int c = 0; c < 8; ++c) pn[c] = pair[j + 8 + c];
#pragma unroll
            for (int c = 0; c < 8; ++c) {
                float msg = relu_(fmaf(__int_as_float(pb[c].y), lw, xv[c] + lb)) + 1e-7f;
                float e = __expf(msg);
                den += e;
                num = fmaf(e, msg, num);
            }
#pragma unroll
            for (int c = 0; c < 8; ++c) pb[c] = pn[c];
        }
        {   // last full 8 (pairs already in registers)
            float xv[8];
#pragma unroll
            for (int c = 0; c < 8; ++c)
                xv[c] = __half2float(xsrc[(size_t)pb[c].x * 64 + lane]);
#pragma unroll
            for (int c = 0; c < 8; ++c) {
                float msg = relu_(fmaf(__int_as_float(pb[c].y), lw, xv[c] + lb)) + 1e-7f;
                float e = __expf(msg);
                den += e;
                num = fmaf(e, msg, num);
            }
            j += 8;
        }
    }
    for (; j < end; ++j) {
        int2 p = pair[j];
        float xv = __half2float(xsrc[(size_t)p.x * 64 + lane]);
        float msg = relu_(fmaf(__int_as_float(p.y), lw, xv + lb)) + 1e-7f;
        float e = __expf(msg);
        den += e;
        num = fmaf(e, msg, num);
    }

    oa[(size_t)n * 64 + lane] = num / (den + 1e-16f) + xd;
}

// ---------------- MLP (pred head extracted): 64->128->64 -------------------
__global__ __launch_bounds__(256, 4) void mlp_kernel(
    const float* __restrict__ oa,    // [N,64]
    float* __restrict__ feat,        // [N,64]
    __half* __restrict__ feat16,     // [N,64] fp16 mirror
    float* __restrict__ snap,        // [N,64] snapshot or nullptr
    const float* __restrict__ w1,    // [64,128]
    const float* __restrict__ b1,    // [128]
    const float* __restrict__ w2,    // [128,64]
    const float* __restrict__ b2,    // [64]
    int N)
{
    __shared__ float act[TN][68];
    __shared__ float hid[TN][132];
    __shared__ float b1s[128];
    __shared__ float b2s[64];

    int tid = threadIdx.x;
    if (tid < 128) b1s[tid] = b1[tid];
    if (tid < 64) b2s[tid] = b2[tid];

    int o4 = (tid & 31) * 4;
    int o2 = (tid & 31) * 2;
    int n5 = (tid >> 5) * 5;
    __syncthreads();

    int ntiles = N / TN;
    for (int tile = blockIdx.x; tile < ntiles; tile += gridDim.x) {
        int base = tile * TN;
        {
            const float4* g4 = (const float4*)(oa + (size_t)base * 64);
            for (int i = tid; i < TN * 16; i += 256)
                *(float4*)&act[i >> 4][(i & 15) * 4] = g4[i];
        }
        __syncthreads();

        {
            float acc[5][4];
#pragma unroll
            for (int i = 0; i < 5; ++i)
#pragma unroll
                for (int q = 0; q < 4; ++q) acc[i][q] = b1s[o4 + q];
#pragma unroll 2
            for (int k = 0; k < 64; k += 4) {
                float4 a[5];
#pragma unroll
                for (int i = 0; i < 5; ++i) a[i] = *(const float4*)&act[n5 + i][k];
                float4 w0 = *(const float4*)&w1[(k + 0) * 128 + o4];
                float4 wq1 = *(const float4*)&w1[(k + 1) * 128 + o4];
                float4 wq2 = *(const float4*)&w1[(k + 2) * 128 + o4];
                float4 wq3 = *(const float4*)&w1[(k + 3) * 128 + o4];
#pragma unroll
                for (int i = 0; i < 5; ++i) {
                    acc[i][0] = fmaf(a[i].x, w0.x, acc[i][0]);
                    acc[i][1] = fmaf(a[i].x, w0.y, acc[i][1]);
                    acc[i][2] = fmaf(a[i].x, w0.z, acc[i][2]);
                    acc[i][3] = fmaf(a[i].x, w0.w, acc[i][3]);
                    acc[i][0] = fmaf(a[i].y, wq1.x, acc[i][0]);
                    acc[i][1] = fmaf(a[i].y, wq1.y, acc[i][1]);
                    acc[i][2] = fmaf(a[i].y, wq1.z, acc[i][2]);
                    acc[i][3] = fmaf(a[i].y, wq1.w, acc[i][3]);
                    acc[i][0] = fmaf(a[i].z, wq2.x, acc[i][0]);
                    acc[i][1] = fmaf(a[i].z, wq2.y, acc[i][1]);
                    acc[i][2] = fmaf(a[i].z, wq2.z, acc[i][2]);
                    acc[i][3] = fmaf(a[i].z, wq2.w, acc[i][3]);
                    acc[i][0] = fmaf(a[i].w, wq3.x, acc[i][0]);
                    acc[i][1] = fmaf(a[i].w, wq3.y, acc[i][1]);
                    acc[i][2] = fmaf(a[i].w, wq3.z, acc[i][2]);
                    acc[i][3] = fmaf(a[i].w, wq3.w, acc[i][3]);
                }
            }
#pragma unroll
            for (int i = 0; i < 5; ++i) {
                float4 h4 = make_float4(relu_(acc[i][0]), relu_(acc[i][1]),
                                        relu_(acc[i][2]), relu_(acc[i][3]));
                *(float4*)&hid[n5 + i][o4] = h4;
            }
        }
        __syncthreads();

        {
            float acc[5][2];
#pragma unroll
            for (int i = 0; i < 5; ++i) { acc[i][0] = b2s[o2]; acc[i][1] = b2s[o2 + 1]; }
#pragma unroll 2
            for (int k = 0; k < 128; k += 4) {
                float4 a[5];
#pragma unroll
                for (int i = 0; i < 5; ++i) a[i] = *(const float4*)&hid[n5 + i][k];
                float2 w0 = *(const float2*)&w2[(k + 0) * 64 + o2];
                float2 wq1 = *(const float2*)&w2[(k + 1) * 64 + o2];
                float2 wq2 = *(const float2*)&w2[(k + 2) * 64 + o2];
                float2 wq3 = *(const float2*)&w2[(k + 3) * 64 + o2];
#pragma unroll
                for (int i = 0; i < 5; ++i) {
                    acc[i][0] = fmaf(a[i].x, w0.x, acc[i][0]);
                    acc[i][1] = fmaf(a[i].x, w0.y, acc[i][1]);
                    acc[i][0] = fmaf(a[i].y, wq1.x, acc[i][0]);
                    acc[i][1] = fmaf(a[i].y, wq1.y, acc[i][1]);
                    acc[i][0] = fmaf(a[i].z, wq2.x, acc[i][0]);
                    acc[i][1] = fmaf(a[i].z, wq2.y, acc[i][1]);
                    acc[i][0] = fmaf(a[i].w, wq3.x, acc[i][0]);
                    acc[i][1] = fmaf(a[i].w, wq3.y, acc[i][1]);
                }
            }
#pragma unroll
            for (int i = 0; i < 5; ++i) {
                float2 r2 = make_float2(acc[i][0], acc[i][1]);
                size_t off = (size_t)(base + n5 + i) * 64 + o2;
                *(float2*)&feat[off] = r2;
                if (snap) *(float2*)&snap[off] = r2;
                *(__half2*)&feat16[off] = __floats2half2_rn(r2.x, r2.y);
            }
        }
        __syncthreads();
    }
}

// ---------------- Batched pred head: all 6 (side,layer) sources ------------
__global__ __launch_bounds__(256, 4) void pred_kernel(
    const float* __restrict__ snap,   // [2][SNAPL][N*64]
    const float* __restrict__ featv,  // [N*64] layer-2 vals
    const float* __restrict__ featc,  // [N*64] layer-2 cons
    const float* __restrict__ pv_w1, const float* __restrict__ pv_b1,
    const float* __restrict__ pv_w2, const float* __restrict__ pv_b2,
    const float* __restrict__ pc_w1, const float* __restrict__ pc_b1,
    const float* __restrict__ pc_w2, const float* __restrict__ pc_b2,
    float* __restrict__ out)          // [2][N*NLAYER]
{
    __shared__ float act[TN][68];
    __shared__ float pb1s[64];
    __shared__ float pw2s[64];

    int bid = blockIdx.x;
    int side  = bid / (NLAYER * NTILES);          // 0 = vals, 1 = cons
    int rem   = bid % (NLAYER * NTILES);
    int layer = rem / NTILES;
    int tile  = rem % NTILES;

    const float* pw1 = side ? pc_w1 : pv_w1;
    const float* pb1 = side ? pc_b1 : pv_b1;
    const float* pw2 = side ? pc_w2 : pv_w2;
    const float* pb2 = side ? pc_b2 : pv_b2;
    const float* src;
    if (layer == NLAYER - 1)
        src = side ? featc : featv;
    else
        src = snap + ((size_t)side * SNAPL + layer) * ((size_t)NVN * 64);
    float* outp = out + (size_t)side * NVN * NLAYER;

    int tid = threadIdx.x;
    if (tid < 64) { pb1s[tid] = pb1[tid]; pw2s[tid] = pw2[tid]; }
    float pb2v = pb2[0];

    int o2 = (tid & 31) * 2;
    int n5 = (tid >> 5) * 5;
    int base = tile * TN;

    {
        const float4* g4 = (const float4*)(src + (size_t)base * 64);
        for (int i = tid; i < TN * 16; i += 256)
            *(float4*)&act[i >> 4][(i & 15) * 4] = g4[i];
    }
    __syncthreads();

    float acc[5][2];
#pragma unroll
    for (int i = 0; i < 5; ++i) { acc[i][0] = pb1s[o2]; acc[i][1] = pb1s[o2 + 1]; }
#pragma unroll 2
    for (int k = 0; k < 64; k += 4) {
        float4 a[5];
#pragma unroll
        for (int i = 0; i < 5; ++i) a[i] = *(const float4*)&act[n5 + i][k];
        float2 w0 = *(const float2*)&pw1[(k + 0) * 64 + o2];
        float2 wq1 = *(const float2*)&pw1[(k + 1) * 64 + o2];
        float2 wq2 = *(const float2*)&pw1[(k + 2) * 64 + o2];
        float2 wq3 = *(const float2*)&pw1[(k + 3) * 64 + o2];
#pragma unroll
        for (int i = 0; i < 5; ++i) {
            acc[i][0] = fmaf(a[i].x, w0.x, acc[i][0]);
            acc[i][1] = fmaf(a[i].x, w0.y, acc[i][1]);
            acc[i][0] = fmaf(a[i].y, wq1.x, acc[i][0]);
            acc[i][1] = fmaf(a[i].y, wq1.y, acc[i][1]);
            acc[i][0] = fmaf(a[i].z, wq2.x, acc[i][0]);
            acc[i][1] = fmaf(a[i].z, wq2.y, acc[i][1]);
            acc[i][0] = fmaf(a[i].w, wq3.x, acc[i][0]);
            acc[i][1] = fmaf(a[i].w, wq3.y, acc[i][1]);
        }
    }
    float pw2a = pw2s[o2], pw2b = pw2s[o2 + 1];
    float ps[5];
#pragma unroll
    for (int i = 0; i < 5; ++i)
        ps[i] = relu_(acc[i][0]) * pw2a + relu_(acc[i][1]) * pw2b;
#pragma unroll
    for (int msk = 16; msk >= 1; msk >>= 1) {
#pragma unroll
        for (int i = 0; i < 5; ++i)
            ps[i] += __shfl_xor(ps[i], msk, 64);
    }
    if ((tid & 31) == 0) {
#pragma unroll
        for (int i = 0; i < 5; ++i)
            outp[(size_t)(base + n5 + i) * NLAYER + layer] = ps[i] + pb2v;
    }
}

extern "C" void kernel_launch(void* const* d_in, const int* in_sizes, int n_in,
                              void* d_out, int out_size, void* d_ws, size_t ws_size,
                              hipStream_t stream)
{
    const float* x_vals   = (const float*)d_in[0];
    const float* x_cons   = (const float*)d_in[1];
    const float* pe_vals  = (const float*)d_in[2];
    const float* pe_cons  = (const float*)d_in[3];
    const int*   ei_v2c   = (const int*)d_in[4];   // [2,E]
    const int*   ei_c2v   = (const int*)d_in[5];   // [2,E]
    const float* ew_v2c   = (const float*)d_in[6]; // [E,1]
    const float* ew_c2v   = (const float*)d_in[7];
    const float* enc_vals_w = (const float*)d_in[8];
    const float* enc_vals_b = (const float*)d_in[9];
    const float* pe_vals_w1 = (const float*)d_in[10];
    const float* pe_vals_b1 = (const float*)d_in[11];
    const float* pe_vals_w2 = (const float*)d_in[12];
    const float* pe_vals_b2 = (const float*)d_in[13];
    const float* enc_cons_w = (const float*)d_in[14];
    const float* enc_cons_b = (const float*)d_in[15];
    const float* pe_cons_w1 = (const float*)d_in[16];
    const float* pe_cons_b1 = (const float*)d_in[17];
    const float* pe_cons_w2 = (const float*)d_in[18];
    const float* pe_cons_b2 = (const float*)d_in[19];
    const float* v2c_edge_w = (const float*)d_in[20]; // [NL,1,64]
    const float* v2c_edge_b = (const float*)d_in[21]; // [NL,64]
    const float* v2c_w1     = (const float*)d_in[22]; // [NL,64,128]
    const float* v2c_b1     = (const float*)d_in[23]; // [NL,128]
    const float* v2c_w2     = (const float*)d_in[24]; // [NL,128,64]
    const float* v2c_b2     = (const float*)d_in[25]; // [NL,64]
    const float* c2v_edge_w = (const float*)d_in[26];
    const float* c2v_edge_b = (const float*)d_in[27];
    const float* c2v_w1     = (const float*)d_in[28];
    const float* c2v_b1     = (const float*)d_in[29];
    const float* c2v_w2     = (const float*)d_in[30];
    const float* c2v_b2     = (const float*)d_in[31];
    const float* pred_vals_w1 = (const float*)d_in[32];
    const float* pred_vals_b1 = (const float*)d_in[33];
    const float* pred_vals_w2 = (const float*)d_in[34];
    const float* pred_vals_b2 = (const float*)d_in[35];
    const float* pred_cons_w1 = (const float*)d_in[36];
    const float* pred_cons_b1 = (const float*)d_in[37];
    const float* pred_cons_w2 = (const float*)d_in[38];
    const float* pred_cons_b2 = (const float*)d_in[39];

    float* out = (float*)d_out;

    const size_t NF = (size_t)NVN * 64;

    // Workspace layout == R8's proven footprint (no growth).
    // snap (2 x SNAPL x NF = 20.48 MB) aliases the stage buffers (20.71 MB):
    // stage is dead after scatter_p2, before any mlp.
    float* ws     = (float*)d_ws;
    float* feat_v = ws;                 // NF
    float* feat_c = feat_v + NF;        // NF
    float* oa     = feat_c + NF;        // NF
    int2* v2c_pair  = (int2*)(oa + NF);        // NBCAP
    int2* c2v_pair  = v2c_pair + NBCAP;        // NBCAP
    int2* v2c_stage = c2v_pair + NBCAP;        // NBCAP
    int2* c2v_stage = v2c_stage + NBCAP;       // NBCAP (contiguous w/ v2c_stage)
    float* snap = (float*)v2c_stage;           // alias: [2][SNAPL][NF]
    __half* feat16_v = (__half*)(c2v_stage + NBCAP);   // NF halfs
    __half* feat16_c = feat16_v + NF;                  // NF halfs
    int* ip = (int*)(feat16_c + NF);
    int* v2c_bincur  = ip; ip += NB;
    int* c2v_bincur  = ip; ip += NB;
    int* v2c_rowptr  = ip; ip += NCN;
    int* v2c_rowend  = ip; ip += NCN;
    int* c2v_rowptr  = ip; ip += NVN;
    int* c2v_rowend  = ip; ip += NVN;

    const int p1b = (NE + P1E - 1) / P1E;   // 245

    // CSR build (single-pass binning: no histogram/scan passes)
    bininit_kernel<<<1, 256, 0, stream>>>(v2c_bincur, c2v_bincur);
    scatter_p1_kernel<<<p1b, 256, 0, stream>>>(
        ei_v2c, ew_v2c, v2c_bincur, v2c_stage,
        ei_c2v, ew_c2v, c2v_bincur, c2v_stage);
    scatter_p2_kernel<<<2 * NB, 1024, 0, stream>>>(
        v2c_bincur, v2c_stage, v2c_rowptr, v2c_rowend, v2c_pair,
        c2v_bincur, c2v_stage, c2v_rowptr, c2v_rowend, c2v_pair);

    // Encoders
    encode2_kernel<<<(NVN + 3) / 4 + (NCN + 3) / 4, 256, 0, stream>>>(
        x_vals, pe_vals, enc_vals_w, enc_vals_b,
        pe_vals_w1, pe_vals_b1, pe_vals_w2, pe_vals_b2,
        x_cons, pe_cons, enc_cons_w, enc_cons_b,
        pe_cons_w1, pe_cons_b1, pe_cons_w2, pe_cons_b2,
        feat_v, feat_c, feat16_v, feat16_c);

    for (int i = 0; i < NLAYER; ++i) {
        float* snap_c = (i < SNAPL) ? snap + ((size_t)SNAPL + i) * NF : nullptr;
        float* snap_v = (i < SNAPL) ? snap + (size_t)i * NF : nullptr;
        // v2c: src = vals (fp16 mirror), dst = cons
        edge_agg_kernel<<<(NCN + 3) / 4, 256, 0, stream>>>(
            feat16_v, feat_c, v2c_rowptr, v2c_rowend, v2c_pair,
            v2c_edge_w + (size_t)i * HID, v2c_edge_b + (size_t)i * HID,
            oa, NCN);
        mlp_kernel<<<NCN / TN, 256, 0, stream>>>(
            oa, feat_c, feat16_c, snap_c,
            v2c_w1 + (size_t)i * 8192, v2c_b1 + (size_t)i * 128,
            v2c_w2 + (size_t)i * 8192, v2c_b2 + (size_t)i * 64,
            NCN);
        // c2v: src = cons (updated fp16 mirror), dst = vals
        edge_agg_kernel<<<(NVN + 3) / 4, 256, 0, stream>>>(
            feat16_c, feat_v, c2v_rowptr, c2v_rowend, c2v_pair,
            c2v_edge_w + (size_t)i * HID, c2v_edge_b + (size_t)i * HID,
            oa, NVN);
        mlp_kernel<<<NVN / TN, 256, 0, stream>>>(
            oa, feat_v, feat16_v, snap_v,
            c2v_w1 + (size_t)i * 8192, c2v_b1 + (size_t)i * 128,
            c2v_w2 + (size_t)i * 8192, c2v_b2 + (size_t)i * 64,
            NVN);
    }

    // Batched pred head over all 6 (side,layer) sources
    pred_kernel<<<2 * NLAYER * NTILES, 256, 0, stream>>>(
        snap, feat_v, feat_c,
        pred_vals_w1, pred_vals_b1, pred_vals_w2, pred_vals_b2,
        pred_cons_w1, pred_cons_b1, pred_cons_w2, pred_cons_b2,
        out);
}